// Round 4
// baseline (881.543 us; speedup 1.0000x reference)
//
#include <hip/hip_runtime.h>
#include <hip/hip_bf16.h>

// Round 4: kNN distance cross-term computed as a sequential FMA chain
// (emulating BLAS sgemm K=3 accumulation, which both the np-optimize=True
// einsum path and the jax/XLA f32 GEMM use):
//   e = fma(qz,pz, fma(qy,py, rn(qx*px))); d = (qq - rn(2*e)) + pp
// qq/pp stay non-FMA (np.sum of elementwise squares). Keys are f32-based so
// equal-f32 ties break by index == stable sort. Rest identical to R3.

#define EPS 1e-5f

constexpr int Bb   = 8;
constexpr int Np   = 8192;
constexpr int Mq   = 2048;
constexpr int CIN  = 64;
constexpr int COUT = 128;
constexpr int BM   = Bb * Mq;        // 16384
constexpr int BMK  = BM * 16;        // 262144

// ---------------- kNN: one wave per query; distributed sorted top-16.
__global__ __launch_bounds__(256) void knn_kernel(const float* __restrict__ p,
                                                  const float* __restrict__ q,
                                                  int* __restrict__ idx_out) {
  int wave = blockIdx.x * 4 + (threadIdx.x >> 6);
  int lane = threadIdx.x & 63;
  int b = wave >> 11;  // Mq = 2048
  const float* pb = p + (size_t)b * Np * 3;
  const float* qp = q + (size_t)wave * 3;
  float qx = qp[0], qy = qp[1], qz = qp[2];
  float qq = __fadd_rn(__fadd_rn(__fmul_rn(qx, qx), __fmul_rn(qy, qy)), __fmul_rn(qz, qz));
  unsigned long long key = ~0ULL;
  unsigned long long tau = ~0ULL;
  for (int base = 0; base < Np; base += 64) {
    int i = base + lane;
    float px = pb[3 * i], py = pb[3 * i + 1], pz = pb[3 * i + 2];
    float pp = __fadd_rn(__fadd_rn(__fmul_rn(px, px), __fmul_rn(py, py)), __fmul_rn(pz, pz));
    // BLAS-style K=3 FMA accumulation chain:
    float e  = __fmaf_rn(qz, pz, __fmaf_rn(qy, py, __fmul_rn(qx, px)));
    float d  = __fadd_rn(__fsub_rn(qq, __fmul_rn(2.0f, e)), pp);
    unsigned u = __float_as_uint(d);
    u ^= ((unsigned)(((int)u) >> 31)) | 0x80000000u;  // IEEE total-order map
    unsigned long long cand = (((unsigned long long)u) << 32) | (unsigned)i;
    unsigned long long mask = __ballot(cand < tau);
    if (mask) {
      do {
        int src = __ffsll((unsigned long long)mask) - 1;
        mask &= mask - 1;
        unsigned long long ck = __shfl(cand, src);
        unsigned long long up = __shfl_up(key, 1);
        if (lane == 0) up = 0ULL;
        if (lane < 16 && ck < key) key = (up > ck) ? up : ck;
      } while (mask);
      tau = __shfl(key, 15);
    }
  }
  if (lane < 16) idx_out[wave * 16 + lane] = (int)(key & 0xffffffffULL);
}

// ---------------- x [B][CIN][N] -> xt [B][N][CIN]
__global__ __launch_bounds__(256) void transpose_x_kernel(const float* __restrict__ x,
                                                          float* __restrict__ xt) {
  __shared__ float tile[64][65];
  int b = blockIdx.x >> 7;
  int n0 = (blockIdx.x & 127) << 6;
  int nl = threadIdx.x & 63;
  int r0 = threadIdx.x >> 6;
  const float* xb = x + (size_t)b * CIN * Np;
  for (int c = r0; c < 64; c += 4) tile[c][nl] = xb[(size_t)c * Np + n0 + nl];
  __syncthreads();
  float* xtb = xt + (size_t)b * Np * 64;
  for (int n = r0; n < 64; n += 4) xtb[(size_t)(n0 + n) * 64 + nl] = tile[nl][n];
}

// ---------------- gather p_hat + mlp layer 1 pre-activation. 1 thread per (b,m,k).
__global__ __launch_bounds__(256) void phat_pre1_kernel(const float* __restrict__ p,
                                                        const float* __restrict__ q,
                                                        const int* __restrict__ idx,
                                                        const float* __restrict__ W1,
                                                        const float* __restrict__ b1,
                                                        float* __restrict__ phat,
                                                        float* __restrict__ pre1) {
  __shared__ float w[96], bb[32];
  if (threadIdx.x < 96) w[threadIdx.x] = W1[threadIdx.x];
  if (threadIdx.x < 32) bb[threadIdx.x] = b1[threadIdx.x];
  __syncthreads();
  int bmk = blockIdx.x * 256 + threadIdx.x;
  int bm = bmk >> 4;
  int b = bm >> 11;
  int j = idx[bmk];
  const float* pp = p + ((size_t)b * Np + j) * 3;
  const float* qp = q + (size_t)bm * 3;
  float h0 = pp[0] - qp[0], h1 = pp[1] - qp[1], h2 = pp[2] - qp[2];
  phat[(size_t)bmk * 3 + 0] = h0;
  phat[(size_t)bmk * 3 + 1] = h1;
  phat[(size_t)bmk * 3 + 2] = h2;
  float r[32];
#pragma unroll
  for (int o = 0; o < 32; ++o)
    r[o] = bb[o] + w[o * 3] * h0 + w[o * 3 + 1] * h1 + w[o * 3 + 2] * h2;
  float4* dst = (float4*)(pre1 + (size_t)bmk * 32);
#pragma unroll
  for (int c4 = 0; c4 < 8; ++c4) dst[c4] = *(float4*)&r[c4 * 4];
}

// ---------------- per-channel sum & sumsq (channel-last, C pow2, C<=256)
__global__ __launch_bounds__(256) void colsum_kernel(const float* __restrict__ X, int n, int C,
                                                     float* __restrict__ sums) {
  __shared__ float ls[512];
  for (int i = threadIdx.x; i < 2 * C; i += 256) ls[i] = 0.f;
  __syncthreads();
  int start = blockIdx.x * 256 + threadIdx.x;
  int stride = gridDim.x * 256;
  float s = 0.f, s2 = 0.f;
  for (int i = start; i < n; i += stride) {
    float v = X[i];
    s += v;
    s2 += v * v;
  }
  int c = threadIdx.x & (C - 1);
  atomicAdd(&ls[c], s);
  atomicAdd(&ls[C + c], s2);
  __syncthreads();
  for (int i = threadIdx.x; i < 2 * C; i += 256) atomicAdd(&sums[i], ls[i]);
}

// ---------------- bn1+relu, then mlp layer 2 pre-activation. 1 thread per (b,m,k).
__global__ __launch_bounds__(256) void h1_pre2_kernel(const float* __restrict__ pre1,
                                                      const float* __restrict__ sums1,
                                                      const float* __restrict__ g1,
                                                      const float* __restrict__ be1,
                                                      const float* __restrict__ W2,
                                                      const float* __restrict__ b2,
                                                      float* __restrict__ pre2) {
  __shared__ float sc[32], sh[32], w2[32 * 33], b2s[32];
  if (threadIdx.x < 32) {
    int c = threadIdx.x;
    float n = (float)BMK;
    float mean = sums1[c] / n;
    float var = sums1[32 + c] / n - mean * mean;
    float s = g1[c] * rsqrtf(var + EPS);
    sc[c] = s;
    sh[c] = be1[c] - mean * s;
    b2s[c] = b2[c];
  }
  for (int e = threadIdx.x; e < 1024; e += 256) w2[(e >> 5) * 33 + (e & 31)] = W2[e];
  __syncthreads();
  int bmk = blockIdx.x * 256 + threadIdx.x;
  float h[32];
  const float4* p1 = (const float4*)(pre1 + (size_t)bmk * 32);
#pragma unroll
  for (int c4 = 0; c4 < 8; ++c4) {
    float4 v = p1[c4];
    h[c4 * 4 + 0] = fmaxf(0.f, v.x * sc[c4 * 4 + 0] + sh[c4 * 4 + 0]);
    h[c4 * 4 + 1] = fmaxf(0.f, v.y * sc[c4 * 4 + 1] + sh[c4 * 4 + 1]);
    h[c4 * 4 + 2] = fmaxf(0.f, v.z * sc[c4 * 4 + 2] + sh[c4 * 4 + 2]);
    h[c4 * 4 + 3] = fmaxf(0.f, v.w * sc[c4 * 4 + 3] + sh[c4 * 4 + 3]);
  }
  float r[32];
#pragma unroll
  for (int o = 0; o < 32; ++o) {
    float a = b2s[o];
#pragma unroll
    for (int c = 0; c < 32; ++c) a += h[c] * w2[o * 33 + c];
    r[o] = a;
  }
  float4* dst = (float4*)(pre2 + (size_t)bmk * 32);
#pragma unroll
  for (int c4 = 0; c4 < 8; ++c4) dst[c4] = *(float4*)&r[c4 * 4];
}

// ---------------- stn conv: pt1[bm][o] = sum_{c,k} phat[bm][k][c]*Ws1[o][c][k] + bs1[o]
__global__ __launch_bounds__(256) void stn1_kernel(const float* __restrict__ phat,
                                                   const float* __restrict__ Ws1,
                                                   const float* __restrict__ bs1,
                                                   float* __restrict__ pt1) {
  __shared__ float w[256 * 49];
  __shared__ float ph[8 * 48];
  int bm0 = blockIdx.x * 8;
  for (int e = threadIdx.x; e < 256 * 48; e += 256) w[(e / 48) * 49 + (e % 48)] = Ws1[e];
  for (int e = threadIdx.x; e < 8 * 48; e += 256) ph[e] = phat[(size_t)bm0 * 48 + e];
  __syncthreads();
  int o = threadIdx.x;
  float acc[8];
  float bias = bs1[o];
#pragma unroll
  for (int j = 0; j < 8; ++j) acc[j] = bias;
#pragma unroll
  for (int c = 0; c < 3; ++c)
#pragma unroll
    for (int k = 0; k < 16; ++k) {
      float wv = w[o * 49 + c * 16 + k];
#pragma unroll
      for (int j = 0; j < 8; ++j) acc[j] += ph[j * 48 + k * 3 + c] * wv;
    }
  for (int j = 0; j < 8; ++j) pt1[(size_t)(bm0 + j) * 256 + o] = acc[j];
}

// ---------------- out[bm][o] = bias[o] + sum_i relu(bn(in[bm][i])) * W[o][i]
__global__ __launch_bounds__(256) void stn_mm_kernel(const float* __restrict__ in,
                                                     const float* __restrict__ sums,
                                                     const float* __restrict__ gg,
                                                     const float* __restrict__ be,
                                                     const float* __restrict__ W,
                                                     const float* __restrict__ bias,
                                                     float* __restrict__ out) {
  __shared__ float tl[32 * 256];
  __shared__ float wl[256 * 17];
  int bm0 = blockIdx.x * 32;
  int tid = threadIdx.x;
  float n = (float)BM;
  float mean = sums[tid] / n;
  float var = sums[256 + tid] / n - mean * mean;
  float s = gg[tid] * rsqrtf(var + EPS);
  float sh = be[tid] - mean * s;
  for (int j = 0; j < 32; ++j) {
    float v = in[(size_t)(bm0 + j) * 256 + tid];
    tl[j * 256 + tid] = fmaxf(0.f, v * s + sh);
  }
  float acc[32];
#pragma unroll
  for (int j = 0; j < 32; ++j) acc[j] = 0.f;
  for (int i0 = 0; i0 < 256; i0 += 16) {
    __syncthreads();
#pragma unroll
    for (int jj = 0; jj < 16; ++jj) {
      int e = tid + jj * 256;
      int o2 = e >> 4, ii = e & 15;
      wl[o2 * 17 + ii] = W[(size_t)o2 * 256 + i0 + ii];
    }
    __syncthreads();
    float wr[16];
#pragma unroll
    for (int ii = 0; ii < 16; ++ii) wr[ii] = wl[tid * 17 + ii];
#pragma unroll
    for (int j = 0; j < 32; ++j) {
      const float4* tj = (const float4*)&tl[j * 256 + i0];
#pragma unroll
      for (int q4 = 0; q4 < 4; ++q4) {
        float4 tv = tj[q4];
        acc[j] += tv.x * wr[q4 * 4 + 0];
        acc[j] += tv.y * wr[q4 * 4 + 1];
        acc[j] += tv.z * wr[q4 * 4 + 2];
        acc[j] += tv.w * wr[q4 * 4 + 3];
      }
    }
  }
  float bv = bias[tid];
  for (int j = 0; j < 32; ++j) out[(size_t)(bm0 + j) * 256 + tid] = acc[j] + bv;
}

// ---------------- Wc [o][c][k] -> Wcr f32 [r=k*96+c][o]
__global__ __launch_bounds__(256) void prep_wcr_kernel(const float* __restrict__ Wc,
                                                       float* __restrict__ Wcr) {
  int g = blockIdx.x * 256 + threadIdx.x;
  if (g >= 1536 * 128) return;
  int r = g >> 7, o = g & 127;
  int c = r % 96, k = r / 96;
  Wcr[g] = Wc[(size_t)o * 1536 + c * 16 + k];
}

// ---------------- build x_hat = [bn2relu(pre2) | gather(xt)] in LDS (f32), x2 = T @ x_hat
__global__ __launch_bounds__(256) void xhat_x2_kernel(const float* __restrict__ pre2,
                                                      const float* __restrict__ sums2,
                                                      const float* __restrict__ g2,
                                                      const float* __restrict__ be2,
                                                      const float* __restrict__ xt,
                                                      const int* __restrict__ idx,
                                                      const float* __restrict__ Tbuf,
                                                      float* __restrict__ x2) {
  __shared__ float xh[256 * 97];
  __shared__ float Tlb[16 * 256];
  __shared__ float sc[32], sh[32];
  int tid = threadIdx.x;
  int bm0 = blockIdx.x * 16;
  int b = bm0 >> 11;
  if (tid < 32) {
    float n = (float)BMK;
    float mean = sums2[tid] / n;
    float var = sums2[32 + tid] / n - mean * mean;
    float s = g2[tid] * rsqrtf(var + EPS);
    sc[tid] = s;
    sh[tid] = be2[tid] - mean * s;
  }
  __syncthreads();
  int bml = tid >> 4, j = tid & 15;
  int bmk = (bm0 + bml) * 16 + j;
  int row = tid * 97;
  {
    const float4* p2 = (const float4*)(pre2 + (size_t)bmk * 32);
#pragma unroll
    for (int c4 = 0; c4 < 8; ++c4) {
      float4 v = p2[c4];
      xh[row + c4 * 4 + 0] = fmaxf(0.f, v.x * sc[c4 * 4 + 0] + sh[c4 * 4 + 0]);
      xh[row + c4 * 4 + 1] = fmaxf(0.f, v.y * sc[c4 * 4 + 1] + sh[c4 * 4 + 1]);
      xh[row + c4 * 4 + 2] = fmaxf(0.f, v.z * sc[c4 * 4 + 2] + sh[c4 * 4 + 2]);
      xh[row + c4 * 4 + 3] = fmaxf(0.f, v.w * sc[c4 * 4 + 3] + sh[c4 * 4 + 3]);
    }
    int jx = idx[bmk];
    const float4* xr = (const float4*)(xt + ((size_t)b * Np + jx) * 64);
#pragma unroll
    for (int c4 = 0; c4 < 16; ++c4) {
      float4 v = xr[c4];
      xh[row + 32 + c4 * 4 + 0] = v.x;
      xh[row + 32 + c4 * 4 + 1] = v.y;
      xh[row + 32 + c4 * 4 + 2] = v.z;
      xh[row + 32 + c4 * 4 + 3] = v.w;
    }
  }
  for (int e = tid; e < 16 * 256; e += 256) Tlb[e] = Tbuf[(size_t)bm0 * 256 + e];
  __syncthreads();
  float Tr[16];
#pragma unroll
  for (int jj = 0; jj < 16; ++jj) Tr[jj] = Tlb[bml * 256 + j * 16 + jj];
#pragma unroll
  for (int c0 = 0; c0 < 96; c0 += 32) {
    float acc[32];
#pragma unroll
    for (int cc = 0; cc < 32; ++cc) acc[cc] = 0.f;
#pragma unroll
    for (int jj = 0; jj < 16; ++jj) {
      const float* xr2 = &xh[(bml * 16 + jj) * 97 + c0];
      float t = Tr[jj];
#pragma unroll
      for (int cc = 0; cc < 32; ++cc) acc[cc] += t * xr2[cc];
    }
    float4* dst = (float4*)(x2 + (size_t)bmk * 96 + c0);
#pragma unroll
    for (int cc = 0; cc < 8; ++cc) dst[cc] = *(float4*)&acc[cc * 4];
  }
}

// ---------------- preout[bm][o] = bc[o] + sum_r x2[bm][r] * Wcr[r][o]   (r = 1536)
__global__ __launch_bounds__(256) void preout_kernel(const float* __restrict__ x2,
                                                     const float* __restrict__ Wcr,
                                                     const float* __restrict__ bc,
                                                     float* __restrict__ pout) {
  __shared__ float al[32 * 64];
  __shared__ float wl[64 * 128];
  int tid = threadIdx.x;
  int bm0 = blockIdx.x * 32;
  int oq = tid & 31, bmq = tid >> 5;
  float acc[4][4];
#pragma unroll
  for (int a = 0; a < 4; ++a)
#pragma unroll
    for (int bcl = 0; bcl < 4; ++bcl) acc[a][bcl] = 0.f;
  for (int i0 = 0; i0 < 1536; i0 += 64) {
    __syncthreads();
#pragma unroll
    for (int jj = 0; jj < 8; ++jj) {
      int e = tid + jj * 256;
      int bm = e >> 6, ii = e & 63;
      al[e] = x2[(size_t)(bm0 + bm) * 1536 + i0 + ii];
    }
#pragma unroll
    for (int jj = 0; jj < 32; ++jj) {
      int e = tid + jj * 256;
      int ii = e >> 7, o = e & 127;
      wl[e] = Wcr[(size_t)(i0 + ii) * 128 + o];
    }
    __syncthreads();
#pragma unroll 8
    for (int ii = 0; ii < 64; ++ii) {
      float4 b4 = *(const float4*)&wl[ii * 128 + oq * 4];
#pragma unroll
      for (int jr = 0; jr < 4; ++jr) {
        float a = al[(bmq * 4 + jr) * 64 + ii];
        acc[jr][0] += a * b4.x;
        acc[jr][1] += a * b4.y;
        acc[jr][2] += a * b4.z;
        acc[jr][3] += a * b4.w;
      }
    }
  }
#pragma unroll
  for (int jr = 0; jr < 4; ++jr) {
    int bm = bm0 + bmq * 4 + jr;
    float4 v;
    v.x = acc[jr][0] + bc[oq * 4 + 0];
    v.y = acc[jr][1] + bc[oq * 4 + 1];
    v.z = acc[jr][2] + bc[oq * 4 + 2];
    v.w = acc[jr][3] + bc[oq * 4 + 3];
    *(float4*)&pout[(size_t)bm * 128 + oq * 4] = v;
  }
}

// ---------------- epilogue: copy q, out[b][o][m] = relu(bnc(pout[b][m][o]))
__global__ __launch_bounds__(256) void final_kernel(const float* __restrict__ q,
                                                    const float* __restrict__ pout,
                                                    const float* __restrict__ scs,
                                                    const float* __restrict__ gc,
                                                    const float* __restrict__ bec,
                                                    float* __restrict__ dout) {
  int g = blockIdx.x * 256 + threadIdx.x;
  if (g < BM * 3) {
    dout[g] = q[g];
    return;
  }
  int g2 = g - BM * 3;
  if (g2 >= Bb * COUT * Mq) return;
  int b = g2 >> 18;
  int rem = g2 & 262143;
  int o = rem >> 11;
  int m = rem & 2047;
  float v = pout[((size_t)(b * Mq + m)) * 128 + o];
  float n = (float)BM;
  float mean = scs[o] / n;
  float var = scs[128 + o] / n - mean * mean;
  float s = gc[o] * rsqrtf(var + EPS);
  float shv = bec[o] - mean * s;
  dout[g] = fmaxf(0.f, v * s + shv);
}

extern "C" void kernel_launch(void* const* d_in, const int* in_sizes, int n_in, void* d_out,
                              int out_size, void* d_ws, size_t ws_size, hipStream_t stream) {
  const float* p = (const float*)d_in[0];
  const float* q = (const float*)d_in[1];
  const float* x = (const float*)d_in[2];
  const float* W1 = (const float*)d_in[3];
  const float* b1 = (const float*)d_in[4];
  const float* g1 = (const float*)d_in[5];
  const float* be1 = (const float*)d_in[6];
  const float* W2 = (const float*)d_in[7];
  const float* b2 = (const float*)d_in[8];
  const float* g2 = (const float*)d_in[9];
  const float* be2 = (const float*)d_in[10];
  const float* Ws1 = (const float*)d_in[11];
  const float* bs1 = (const float*)d_in[12];
  const float* gs1 = (const float*)d_in[13];
  const float* bes1 = (const float*)d_in[14];
  const float* Ws2 = (const float*)d_in[15];
  const float* bs2 = (const float*)d_in[16];
  const float* gs2 = (const float*)d_in[17];
  const float* bes2 = (const float*)d_in[18];
  const float* Ws3 = (const float*)d_in[19];
  const float* bs3 = (const float*)d_in[20];
  const float* Wc = (const float*)d_in[21];
  const float* bc = (const float*)d_in[22];
  const float* gc = (const float*)d_in[23];
  const float* bec = (const float*)d_in[24];
  float* dout = (float*)d_out;

  char* ws = (char*)d_ws;
  // stats floats: sums1@0(64), sums2@64(64), ss1@128(512), ss2@640(512), sc@1152(256)
  float* stats = (float*)ws;
  size_t off = 8192;
  int* idxb = (int*)(ws + off);   off += (size_t)BMK * 4;             // 1 MB
  float* xt = (float*)(ws + off); off += (size_t)Bb * Np * 64 * 4;    // 16 MB
  float* pre2 = (float*)(ws + off); off += (size_t)BMK * 32 * 4;      // 32 MB
  float* pt1 = (float*)(ws + off); off += (size_t)BM * 256 * 4;       // 16 MB
  float* pout = (float*)(ws + off); off += (size_t)BM * 128 * 4;      // 8 MB
  float* wcr = (float*)(ws + off); off += (size_t)1536 * 128 * 4;     // 768 KB
  // pool: phat(3MB)+pre1(32MB)+pt2(16MB) all dead before xhat_x2 writes x2(96MB)
  char* pool = ws + off;
  float* phat = (float*)pool;
  float* pre1 = (float*)(pool + (size_t)BMK * 3 * 4);
  float* pt2 = (float*)(pool + (size_t)BMK * 3 * 4 + (size_t)BMK * 32 * 4);
  float* x2 = (float*)pool;  // 96 MB, aliases phat/pre1/pt2
  float* Tb = pt1;           // reuse: pt1 dead after first stn_mm (NOT in pool)

  hipMemsetAsync(stats, 0, 8192, stream);
  hipLaunchKernelGGL(transpose_x_kernel, dim3(1024), dim3(256), 0, stream, x, xt);
  hipLaunchKernelGGL(knn_kernel, dim3(4096), dim3(256), 0, stream, p, q, idxb);
  hipLaunchKernelGGL(phat_pre1_kernel, dim3(1024), dim3(256), 0, stream, p, q, idxb, W1, b1, phat, pre1);
  hipLaunchKernelGGL(colsum_kernel, dim3(512), dim3(256), 0, stream, pre1, BMK * 32, 32, stats);
  hipLaunchKernelGGL(h1_pre2_kernel, dim3(1024), dim3(256), 0, stream, pre1, stats, g1, be1, W2, b2, pre2);
  hipLaunchKernelGGL(colsum_kernel, dim3(512), dim3(256), 0, stream, pre2, BMK * 32, 32, stats + 64);
  hipLaunchKernelGGL(stn1_kernel, dim3(2048), dim3(256), 0, stream, phat, Ws1, bs1, pt1);
  hipLaunchKernelGGL(colsum_kernel, dim3(512), dim3(256), 0, stream, pt1, BM * 256, 256, stats + 128);
  hipLaunchKernelGGL(stn_mm_kernel, dim3(512), dim3(256), 0, stream, pt1, stats + 128, gs1, bes1, Ws2, bs2, pt2);
  hipLaunchKernelGGL(colsum_kernel, dim3(512), dim3(256), 0, stream, pt2, BM * 256, 256, stats + 640);
  hipLaunchKernelGGL(stn_mm_kernel, dim3(512), dim3(256), 0, stream, pt2, stats + 640, gs2, bes2, Ws3, bs3, Tb);
  hipLaunchKernelGGL(prep_wcr_kernel, dim3(768), dim3(256), 0, stream, Wc, wcr);
  hipLaunchKernelGGL(xhat_x2_kernel, dim3(1024), dim3(256), 0, stream, pre2, stats + 64, g2, be2, xt, idxb, Tb, x2);
  hipLaunchKernelGGL(preout_kernel, dim3(512), dim3(256), 0, stream, x2, wcr, bc, pout);
  hipLaunchKernelGGL(colsum_kernel, dim3(512), dim3(256), 0, stream, pout, BM * 128, 128, stats + 1152);
  hipLaunchKernelGGL(final_kernel, dim3(8384), dim3(256), 0, stream, q, pout, stats + 1152, gc, bec, dout);
}

// Round 5
// 720.009 us; speedup vs baseline: 1.2243x; 1.2243x over previous
//
#include <hip/hip_runtime.h>
#include <hip/hip_bf16.h>

// Round 5: perf. (1) knn: 4-point unroll (distance math byte-identical to R4);
// (2) preout: bf16 MFMA 16x16x32 GEMM (M=16384,N=128,K=1536), x2/Wc in bf16;
// (3) xhat_x2: xh in bf16 + T direct loads -> LDS 115KB -> 50KB (occupancy 1->3 blocks/CU).

#define EPS 1e-5f

constexpr int Bb   = 8;
constexpr int Np   = 8192;
constexpr int Mq   = 2048;
constexpr int CIN  = 64;
constexpr int COUT = 128;
constexpr int BM   = Bb * Mq;        // 16384
constexpr int BMK  = BM * 16;        // 262144

typedef __attribute__((ext_vector_type(8))) short short8;
typedef __attribute__((ext_vector_type(4))) float f32x4;

__device__ __forceinline__ unsigned short f2bf(float x) {
  unsigned u = __float_as_uint(x);
  u += 0x7fffu + ((u >> 16) & 1u);
  return (unsigned short)(u >> 16);
}
__device__ __forceinline__ float bf2f_lo(unsigned v) { return __uint_as_float(v << 16); }
__device__ __forceinline__ float bf2f_hi(unsigned v) { return __uint_as_float(v & 0xffff0000u); }

// ---------------- kNN: one wave per query; distributed sorted top-16.
// 4-point unroll for load ILP; distance math identical to R4 (BLAS FMA chain).
__global__ __launch_bounds__(256) void knn_kernel(const float* __restrict__ p,
                                                  const float* __restrict__ q,
                                                  int* __restrict__ idx_out) {
  int wave = blockIdx.x * 4 + (threadIdx.x >> 6);
  int lane = threadIdx.x & 63;
  int b = wave >> 11;  // Mq = 2048
  const float* pb = p + (size_t)b * Np * 3;
  const float* qp = q + (size_t)wave * 3;
  float qx = qp[0], qy = qp[1], qz = qp[2];
  float qq = __fadd_rn(__fadd_rn(__fmul_rn(qx, qx), __fmul_rn(qy, qy)), __fmul_rn(qz, qz));
  unsigned long long key = ~0ULL;
  unsigned long long tau = ~0ULL;
  for (int base = 0; base < Np; base += 256) {
    unsigned long long cand[4];
#pragma unroll
    for (int u4 = 0; u4 < 4; ++u4) {
      int i = base + u4 * 64 + lane;
      float px = pb[3 * i], py = pb[3 * i + 1], pz = pb[3 * i + 2];
      float pp = __fadd_rn(__fadd_rn(__fmul_rn(px, px), __fmul_rn(py, py)), __fmul_rn(pz, pz));
      float e  = __fmaf_rn(qz, pz, __fmaf_rn(qy, py, __fmul_rn(qx, px)));
      float d  = __fadd_rn(__fsub_rn(qq, __fmul_rn(2.0f, e)), pp);
      unsigned u = __float_as_uint(d);
      u ^= ((unsigned)(((int)u) >> 31)) | 0x80000000u;  // IEEE total-order map
      cand[u4] = (((unsigned long long)u) << 32) | (unsigned)i;
    }
#pragma unroll
    for (int u4 = 0; u4 < 4; ++u4) {
      unsigned long long mask = __ballot(cand[u4] < tau);
      if (mask) {
        do {
          int src = __ffsll((unsigned long long)mask) - 1;
          mask &= mask - 1;
          unsigned long long ck = __shfl(cand[u4], src);
          unsigned long long up = __shfl_up(key, 1);
          if (lane == 0) up = 0ULL;
          if (lane < 16 && ck < key) key = (up > ck) ? up : ck;
        } while (mask);
        tau = __shfl(key, 15);
      }
    }
  }
  if (lane < 16) idx_out[wave * 16 + lane] = (int)(key & 0xffffffffULL);
}

// ---------------- x [B][CIN][N] -> xt [B][N][CIN]
__global__ __launch_bounds__(256) void transpose_x_kernel(const float* __restrict__ x,
                                                          float* __restrict__ xt) {
  __shared__ float tile[64][65];
  int b = blockIdx.x >> 7;
  int n0 = (blockIdx.x & 127) << 6;
  int nl = threadIdx.x & 63;
  int r0 = threadIdx.x >> 6;
  const float* xb = x + (size_t)b * CIN * Np;
  for (int c = r0; c < 64; c += 4) tile[c][nl] = xb[(size_t)c * Np + n0 + nl];
  __syncthreads();
  float* xtb = xt + (size_t)b * Np * 64;
  for (int n = r0; n < 64; n += 4) xtb[(size_t)(n0 + n) * 64 + nl] = tile[nl][n];
}

// ---------------- gather p_hat + mlp layer 1 pre-activation. 1 thread per (b,m,k).
__global__ __launch_bounds__(256) void phat_pre1_kernel(const float* __restrict__ p,
                                                        const float* __restrict__ q,
                                                        const int* __restrict__ idx,
                                                        const float* __restrict__ W1,
                                                        const float* __restrict__ b1,
                                                        float* __restrict__ phat,
                                                        float* __restrict__ pre1) {
  __shared__ float w[96], bb[32];
  if (threadIdx.x < 96) w[threadIdx.x] = W1[threadIdx.x];
  if (threadIdx.x < 32) bb[threadIdx.x] = b1[threadIdx.x];
  __syncthreads();
  int bmk = blockIdx.x * 256 + threadIdx.x;
  int bm = bmk >> 4;
  int b = bm >> 11;
  int j = idx[bmk];
  const float* pp = p + ((size_t)b * Np + j) * 3;
  const float* qp = q + (size_t)bm * 3;
  float h0 = pp[0] - qp[0], h1 = pp[1] - qp[1], h2 = pp[2] - qp[2];
  phat[(size_t)bmk * 3 + 0] = h0;
  phat[(size_t)bmk * 3 + 1] = h1;
  phat[(size_t)bmk * 3 + 2] = h2;
  float r[32];
#pragma unroll
  for (int o = 0; o < 32; ++o)
    r[o] = bb[o] + w[o * 3] * h0 + w[o * 3 + 1] * h1 + w[o * 3 + 2] * h2;
  float4* dst = (float4*)(pre1 + (size_t)bmk * 32);
#pragma unroll
  for (int c4 = 0; c4 < 8; ++c4) dst[c4] = *(float4*)&r[c4 * 4];
}

// ---------------- per-channel sum & sumsq (channel-last, C pow2, C<=256)
__global__ __launch_bounds__(256) void colsum_kernel(const float* __restrict__ X, int n, int C,
                                                     float* __restrict__ sums) {
  __shared__ float ls[512];
  for (int i = threadIdx.x; i < 2 * C; i += 256) ls[i] = 0.f;
  __syncthreads();
  int start = blockIdx.x * 256 + threadIdx.x;
  int stride = gridDim.x * 256;
  float s = 0.f, s2 = 0.f;
  for (int i = start; i < n; i += stride) {
    float v = X[i];
    s += v;
    s2 += v * v;
  }
  int c = threadIdx.x & (C - 1);
  atomicAdd(&ls[c], s);
  atomicAdd(&ls[C + c], s2);
  __syncthreads();
  for (int i = threadIdx.x; i < 2 * C; i += 256) atomicAdd(&sums[i], ls[i]);
}

// ---------------- bn1+relu, then mlp layer 2 pre-activation. 1 thread per (b,m,k).
__global__ __launch_bounds__(256) void h1_pre2_kernel(const float* __restrict__ pre1,
                                                      const float* __restrict__ sums1,
                                                      const float* __restrict__ g1,
                                                      const float* __restrict__ be1,
                                                      const float* __restrict__ W2,
                                                      const float* __restrict__ b2,
                                                      float* __restrict__ pre2) {
  __shared__ float sc[32], sh[32], w2[32 * 33], b2s[32];
  if (threadIdx.x < 32) {
    int c = threadIdx.x;
    float n = (float)BMK;
    float mean = sums1[c] / n;
    float var = sums1[32 + c] / n - mean * mean;
    float s = g1[c] * rsqrtf(var + EPS);
    sc[c] = s;
    sh[c] = be1[c] - mean * s;
    b2s[c] = b2[c];
  }
  for (int e = threadIdx.x; e < 1024; e += 256) w2[(e >> 5) * 33 + (e & 31)] = W2[e];
  __syncthreads();
  int bmk = blockIdx.x * 256 + threadIdx.x;
  float h[32];
  const float4* p1 = (const float4*)(pre1 + (size_t)bmk * 32);
#pragma unroll
  for (int c4 = 0; c4 < 8; ++c4) {
    float4 v = p1[c4];
    h[c4 * 4 + 0] = fmaxf(0.f, v.x * sc[c4 * 4 + 0] + sh[c4 * 4 + 0]);
    h[c4 * 4 + 1] = fmaxf(0.f, v.y * sc[c4 * 4 + 1] + sh[c4 * 4 + 1]);
    h[c4 * 4 + 2] = fmaxf(0.f, v.z * sc[c4 * 4 + 2] + sh[c4 * 4 + 2]);
    h[c4 * 4 + 3] = fmaxf(0.f, v.w * sc[c4 * 4 + 3] + sh[c4 * 4 + 3]);
  }
  float r[32];
#pragma unroll
  for (int o = 0; o < 32; ++o) {
    float a = b2s[o];
#pragma unroll
    for (int c = 0; c < 32; ++c) a += h[c] * w2[o * 33 + c];
    r[o] = a;
  }
  float4* dst = (float4*)(pre2 + (size_t)bmk * 32);
#pragma unroll
  for (int c4 = 0; c4 < 8; ++c4) dst[c4] = *(float4*)&r[c4 * 4];
}

// ---------------- stn conv: pt1[bm][o] = sum_{c,k} phat[bm][k][c]*Ws1[o][c][k] + bs1[o]
__global__ __launch_bounds__(256) void stn1_kernel(const float* __restrict__ phat,
                                                   const float* __restrict__ Ws1,
                                                   const float* __restrict__ bs1,
                                                   float* __restrict__ pt1) {
  __shared__ float w[256 * 49];
  __shared__ float ph[8 * 48];
  int bm0 = blockIdx.x * 8;
  for (int e = threadIdx.x; e < 256 * 48; e += 256) w[(e / 48) * 49 + (e % 48)] = Ws1[e];
  for (int e = threadIdx.x; e < 8 * 48; e += 256) ph[e] = phat[(size_t)bm0 * 48 + e];
  __syncthreads();
  int o = threadIdx.x;
  float acc[8];
  float bias = bs1[o];
#pragma unroll
  for (int j = 0; j < 8; ++j) acc[j] = bias;
#pragma unroll
  for (int c = 0; c < 3; ++c)
#pragma unroll
    for (int k = 0; k < 16; ++k) {
      float wv = w[o * 49 + c * 16 + k];
#pragma unroll
      for (int j = 0; j < 8; ++j) acc[j] += ph[j * 48 + k * 3 + c] * wv;
    }
  for (int j = 0; j < 8; ++j) pt1[(size_t)(bm0 + j) * 256 + o] = acc[j];
}

// ---------------- out[bm][o] = bias[o] + sum_i relu(bn(in[bm][i])) * W[o][i]
__global__ __launch_bounds__(256) void stn_mm_kernel(const float* __restrict__ in,
                                                     const float* __restrict__ sums,
                                                     const float* __restrict__ gg,
                                                     const float* __restrict__ be,
                                                     const float* __restrict__ W,
                                                     const float* __restrict__ bias,
                                                     float* __restrict__ out) {
  __shared__ float tl[32 * 256];
  __shared__ float wl[256 * 17];
  int bm0 = blockIdx.x * 32;
  int tid = threadIdx.x;
  float n = (float)BM;
  float mean = sums[tid] / n;
  float var = sums[256 + tid] / n - mean * mean;
  float s = gg[tid] * rsqrtf(var + EPS);
  float sh = be[tid] - mean * s;
  for (int j = 0; j < 32; ++j) {
    float v = in[(size_t)(bm0 + j) * 256 + tid];
    tl[j * 256 + tid] = fmaxf(0.f, v * s + sh);
  }
  float acc[32];
#pragma unroll
  for (int j = 0; j < 32; ++j) acc[j] = 0.f;
  for (int i0 = 0; i0 < 256; i0 += 16) {
    __syncthreads();
#pragma unroll
    for (int jj = 0; jj < 16; ++jj) {
      int e = tid + jj * 256;
      int o2 = e >> 4, ii = e & 15;
      wl[o2 * 17 + ii] = W[(size_t)o2 * 256 + i0 + ii];
    }
    __syncthreads();
    float wr[16];
#pragma unroll
    for (int ii = 0; ii < 16; ++ii) wr[ii] = wl[tid * 17 + ii];
#pragma unroll
    for (int j = 0; j < 32; ++j) {
      const float4* tj = (const float4*)&tl[j * 256 + i0];
#pragma unroll
      for (int q4 = 0; q4 < 4; ++q4) {
        float4 tv = tj[q4];
        acc[j] += tv.x * wr[q4 * 4 + 0];
        acc[j] += tv.y * wr[q4 * 4 + 1];
        acc[j] += tv.z * wr[q4 * 4 + 2];
        acc[j] += tv.w * wr[q4 * 4 + 3];
      }
    }
  }
  float bv = bias[tid];
  for (int j = 0; j < 32; ++j) out[(size_t)(bm0 + j) * 256 + tid] = acc[j] + bv;
}

// ---------------- Wc [o][c][k] -> Wcrp bf16 [o][r], r = j*96+c  (B^T rows for MFMA)
__global__ __launch_bounds__(256) void prep_wcr_kernel(const float* __restrict__ Wc,
                                                       unsigned short* __restrict__ Wcrp) {
  int g = blockIdx.x * 256 + threadIdx.x;
  if (g >= 128 * 1536) return;
  int o = g / 1536, r = g % 1536;
  int c = r % 96, j = r / 96;
  Wcrp[g] = f2bf(Wc[(size_t)o * 1536 + c * 16 + j]);
}

// ---------------- build x_hat=[bn2relu(pre2)|gather(xt)] (bf16 LDS), x2 = T @ x_hat (bf16 out)
__global__ __launch_bounds__(256) void xhat_x2_kernel(const float* __restrict__ pre2,
                                                      const float* __restrict__ sums2,
                                                      const float* __restrict__ g2,
                                                      const float* __restrict__ be2,
                                                      const float* __restrict__ xt,
                                                      const int* __restrict__ idx,
                                                      const float* __restrict__ Tbuf,
                                                      unsigned short* __restrict__ x2) {
  __shared__ unsigned short xh[256 * 98];  // (bm-local*16+j) rows of 96 bf16 (+2 pad)
  __shared__ float sc[32], sh[32];
  int tid = threadIdx.x;
  int bm0 = blockIdx.x * 16;
  int b = bm0 >> 11;
  if (tid < 32) {
    float n = (float)BMK;
    float mean = sums2[tid] / n;
    float var = sums2[32 + tid] / n - mean * mean;
    float s = g2[tid] * rsqrtf(var + EPS);
    sc[tid] = s;
    sh[tid] = be2[tid] - mean * s;
  }
  __syncthreads();
  int bml = tid >> 4, j = tid & 15;
  int bmk = (bm0 + bml) * 16 + j;
  int row = tid * 98;
  {
    const float4* p2 = (const float4*)(pre2 + (size_t)bmk * 32);
#pragma unroll
    for (int c4 = 0; c4 < 8; ++c4) {
      float4 v = p2[c4];
      float a0 = fmaxf(0.f, v.x * sc[c4 * 4 + 0] + sh[c4 * 4 + 0]);
      float a1 = fmaxf(0.f, v.y * sc[c4 * 4 + 1] + sh[c4 * 4 + 1]);
      float a2 = fmaxf(0.f, v.z * sc[c4 * 4 + 2] + sh[c4 * 4 + 2]);
      float a3 = fmaxf(0.f, v.w * sc[c4 * 4 + 3] + sh[c4 * 4 + 3]);
      *(unsigned*)&xh[row + c4 * 4] = (unsigned)f2bf(a0) | (((unsigned)f2bf(a1)) << 16);
      *(unsigned*)&xh[row + c4 * 4 + 2] = (unsigned)f2bf(a2) | (((unsigned)f2bf(a3)) << 16);
    }
    int jx = idx[bmk];
    const float4* xr = (const float4*)(xt + ((size_t)b * Np + jx) * 64);
#pragma unroll
    for (int c4 = 0; c4 < 16; ++c4) {
      float4 v = xr[c4];
      *(unsigned*)&xh[row + 32 + c4 * 4] = (unsigned)f2bf(v.x) | (((unsigned)f2bf(v.y)) << 16);
      *(unsigned*)&xh[row + 32 + c4 * 4 + 2] = (unsigned)f2bf(v.z) | (((unsigned)f2bf(v.w)) << 16);
    }
  }
  float Tr[16];
  {
    const float4* tg = (const float4*)(Tbuf + (size_t)(bm0 + bml) * 256 + j * 16);
#pragma unroll
    for (int w4 = 0; w4 < 4; ++w4) {
      float4 tv = tg[w4];
      Tr[w4 * 4 + 0] = tv.x; Tr[w4 * 4 + 1] = tv.y;
      Tr[w4 * 4 + 2] = tv.z; Tr[w4 * 4 + 3] = tv.w;
    }
  }
  __syncthreads();
#pragma unroll
  for (int c0 = 0; c0 < 96; c0 += 32) {
    float acc[32];
#pragma unroll
    for (int cc = 0; cc < 32; ++cc) acc[cc] = 0.f;
#pragma unroll
    for (int jj = 0; jj < 16; ++jj) {
      const unsigned* xr2 = (const unsigned*)&xh[(bml * 16 + jj) * 98 + c0];
      float t = Tr[jj];
#pragma unroll
      for (int cc = 0; cc < 16; ++cc) {
        unsigned uv = xr2[cc];
        acc[cc * 2] += t * bf2f_lo(uv);
        acc[cc * 2 + 1] += t * bf2f_hi(uv);
      }
    }
    unsigned* dst = (unsigned*)(x2 + (size_t)bmk * 96 + c0);
#pragma unroll
    for (int cc = 0; cc < 16; ++cc)
      dst[cc] = (unsigned)f2bf(acc[cc * 2]) | (((unsigned)f2bf(acc[cc * 2 + 1])) << 16);
  }
}

// ---------------- preout = x2(bf16) @ Wcrp^T(bf16) + bc, MFMA 16x16x32.
// Block: 64(bm) x 64(o) tile, 4 waves 2x2, each wave 32x32 (2x2 mfma tiles), BK=32.
__global__ __launch_bounds__(256) void preout_kernel(const unsigned short* __restrict__ x2,
                                                     const unsigned short* __restrict__ Wcrp,
                                                     const float* __restrict__ bc,
                                                     float* __restrict__ pout) {
  __shared__ unsigned short As[64 * 40];  // pitch 40 bf16 (80B): 2-way bank spread
  __shared__ unsigned short Bs[64 * 40];
  int tid = threadIdx.x;
  int mb = blockIdx.x >> 1, nb = blockIdx.x & 1;
  int bm0 = mb * 64, o0 = nb * 64;
  int wid = tid >> 6, lane = tid & 63;
  int wm = wid >> 1, wn = wid & 1;
  int mh = lane & 15, quad = lane >> 4;
  f32x4 acc[2][2];
#pragma unroll
  for (int a = 0; a < 2; ++a)
#pragma unroll
    for (int bq = 0; bq < 2; ++bq) acc[a][bq] = (f32x4){0.f, 0.f, 0.f, 0.f};
  int ar = tid >> 2, aseg = tid & 3;  // 64 rows x 4 x 8-elem segments
  const unsigned short* Ag = x2 + (size_t)(bm0 + ar) * 1536 + aseg * 8;
  const unsigned short* Bg = Wcrp + (size_t)(o0 + ar) * 1536 + aseg * 8;
  int aoff = ar * 40 + aseg * 8;
  for (int i0 = 0; i0 < 1536; i0 += 32) {
    __syncthreads();
    *(short8*)&As[aoff] = *(const short8*)(Ag + i0);
    *(short8*)&Bs[aoff] = *(const short8*)(Bg + i0);
    __syncthreads();
#pragma unroll
    for (int mt = 0; mt < 2; ++mt) {
      short8 af = *(const short8*)&As[(wm * 32 + mt * 16 + mh) * 40 + quad * 8];
#pragma unroll
      for (int nt = 0; nt < 2; ++nt) {
        short8 bf = *(const short8*)&Bs[(wn * 32 + nt * 16 + mh) * 40 + quad * 8];
        acc[mt][nt] = __builtin_amdgcn_mfma_f32_16x16x32_bf16(af, bf, acc[mt][nt], 0, 0, 0);
      }
    }
  }
#pragma unroll
  for (int mt = 0; mt < 2; ++mt)
#pragma unroll
    for (int nt = 0; nt < 2; ++nt) {
      int col = o0 + wn * 32 + nt * 16 + mh;
      float bv = bc[col];
#pragma unroll
      for (int r = 0; r < 4; ++r) {
        int rowi = bm0 + wm * 32 + mt * 16 + quad * 4 + r;
        pout[(size_t)rowi * 128 + col] = acc[mt][nt][r] + bv;
      }
    }
}

// ---------------- epilogue: copy q, out[b][o][m] = relu(bnc(pout[b][m][o]))
__global__ __launch_bounds__(256) void final_kernel(const float* __restrict__ q,
                                                    const float* __restrict__ pout,
                                                    const float* __restrict__ scs,
                                                    const float* __restrict__ gc,
                                                    const float* __restrict__ bec,
                                                    float* __restrict__ dout) {
  int g = blockIdx.x * 256 + threadIdx.x;
  if (g < BM * 3) {
    dout[g] = q[g];
    return;
  }
  int g2 = g - BM * 3;
  if (g2 >= Bb * COUT * Mq) return;
  int b = g2 >> 18;
  int rem = g2 & 262143;
  int o = rem >> 11;
  int m = rem & 2047;
  float v = pout[((size_t)(b * Mq + m)) * 128 + o];
  float n = (float)BM;
  float mean = scs[o] / n;
  float var = scs[128 + o] / n - mean * mean;
  float s = gc[o] * rsqrtf(var + EPS);
  float shv = bec[o] - mean * s;
  dout[g] = fmaxf(0.f, v * s + shv);
}

extern "C" void kernel_launch(void* const* d_in, const int* in_sizes, int n_in, void* d_out,
                              int out_size, void* d_ws, size_t ws_size, hipStream_t stream) {
  const float* p = (const float*)d_in[0];
  const float* q = (const float*)d_in[1];
  const float* x = (const float*)d_in[2];
  const float* W1 = (const float*)d_in[3];
  const float* b1 = (const float*)d_in[4];
  const float* g1 = (const float*)d_in[5];
  const float* be1 = (const float*)d_in[6];
  const float* W2 = (const float*)d_in[7];
  const float* b2 = (const float*)d_in[8];
  const float* g2 = (const float*)d_in[9];
  const float* be2 = (const float*)d_in[10];
  const float* Ws1 = (const float*)d_in[11];
  const float* bs1 = (const float*)d_in[12];
  const float* gs1 = (const float*)d_in[13];
  const float* bes1 = (const float*)d_in[14];
  const float* Ws2 = (const float*)d_in[15];
  const float* bs2 = (const float*)d_in[16];
  const float* gs2 = (const float*)d_in[17];
  const float* bes2 = (const float*)d_in[18];
  const float* Ws3 = (const float*)d_in[19];
  const float* bs3 = (const float*)d_in[20];
  const float* Wc = (const float*)d_in[21];
  const float* bc = (const float*)d_in[22];
  const float* gc = (const float*)d_in[23];
  const float* bec = (const float*)d_in[24];
  float* dout = (float*)d_out;

  char* ws = (char*)d_ws;
  // stats floats: sums1@0(64), sums2@64(64), ss1@128(512), ss2@640(512), sc@1152(256)
  float* stats = (float*)ws;
  size_t off = 8192;
  int* idxb = (int*)(ws + off);   off += (size_t)BMK * 4;             // 1 MB
  float* xt = (float*)(ws + off); off += (size_t)Bb * Np * 64 * 4;    // 16 MB
  float* pre2 = (float*)(ws + off); off += (size_t)BMK * 32 * 4;      // 32 MB
  float* pt1 = (float*)(ws + off); off += (size_t)BM * 256 * 4;       // 16 MB
  float* pout = (float*)(ws + off); off += (size_t)BM * 128 * 4;      // 8 MB
  unsigned short* wcrp = (unsigned short*)(ws + off); off += (size_t)1536 * 128 * 4;
  // pool: phat(3MB)+pre1(32MB)+pt2(16MB) all dead before xhat_x2 writes x2 (48MB bf16)
  char* pool = ws + off;
  float* phat = (float*)pool;
  float* pre1 = (float*)(pool + (size_t)BMK * 3 * 4);
  float* pt2 = (float*)(pool + (size_t)BMK * 3 * 4 + (size_t)BMK * 32 * 4);
  unsigned short* x2 = (unsigned short*)pool;  // 48 MB, aliases phat/pre1/(head of)pt2
  float* Tb = pt1;  // reuse: pt1 dead after first stn_mm (NOT in pool)

  hipMemsetAsync(stats, 0, 8192, stream);
  hipLaunchKernelGGL(transpose_x_kernel, dim3(1024), dim3(256), 0, stream, x, xt);
  hipLaunchKernelGGL(knn_kernel, dim3(4096), dim3(256), 0, stream, p, q, idxb);
  hipLaunchKernelGGL(phat_pre1_kernel, dim3(1024), dim3(256), 0, stream, p, q, idxb, W1, b1, phat, pre1);
  hipLaunchKernelGGL(colsum_kernel, dim3(512), dim3(256), 0, stream, pre1, BMK * 32, 32, stats);
  hipLaunchKernelGGL(h1_pre2_kernel, dim3(1024), dim3(256), 0, stream, pre1, stats, g1, be1, W2, b2, pre2);
  hipLaunchKernelGGL(colsum_kernel, dim3(512), dim3(256), 0, stream, pre2, BMK * 32, 32, stats + 64);
  hipLaunchKernelGGL(stn1_kernel, dim3(2048), dim3(256), 0, stream, phat, Ws1, bs1, pt1);
  hipLaunchKernelGGL(colsum_kernel, dim3(512), dim3(256), 0, stream, pt1, BM * 256, 256, stats + 128);
  hipLaunchKernelGGL(stn_mm_kernel, dim3(512), dim3(256), 0, stream, pt1, stats + 128, gs1, bes1, Ws2, bs2, pt2);
  hipLaunchKernelGGL(colsum_kernel, dim3(512), dim3(256), 0, stream, pt2, BM * 256, 256, stats + 640);
  hipLaunchKernelGGL(stn_mm_kernel, dim3(512), dim3(256), 0, stream, pt2, stats + 640, gs2, bes2, Ws3, bs3, Tb);
  hipLaunchKernelGGL(prep_wcr_kernel, dim3(768), dim3(256), 0, stream, Wc, wcrp);
  hipLaunchKernelGGL(xhat_x2_kernel, dim3(1024), dim3(256), 0, stream, pre2, stats + 64, g2, be2, xt, idxb, Tb, x2);
  hipLaunchKernelGGL(preout_kernel, dim3(512), dim3(256), 0, stream, x2, wcrp, bc, pout);
  hipLaunchKernelGGL(colsum_kernel, dim3(512), dim3(256), 0, stream, pout, BM * 128, 128, stats + 1152);
  hipLaunchKernelGGL(final_kernel, dim3(8384), dim3(256), 0, stream, q, pout, stats + 1152, gc, bec, dout);
}